// Round 3
// baseline (141.538 us; speedup 1.0000x reference)
//
#include <hip/hip_runtime.h>
#include <hip/hip_bf16.h>

#define Bdim 256
#define Sdim 196
#define Hdim 1024
#define Fdim 2048
#define BH (Bdim*Hdim)      // 262144
#define L2E 1.44269504f
#define C2L 2.88539008f     // 2*log2(e)

// ---------------- Kernel A: q partials = ha@W_ha^T + hf@W_hf^T (K-split) --------
#define TM 64
#define TN 128
#define TK 32

__global__ __launch_bounds__(256) void gemm_q_part(
    const float* __restrict__ ha, const float* __restrict__ hf,
    const float* __restrict__ Wha, const float* __restrict__ Whf,
    float* __restrict__ qpart, int kchunk)
{
    __shared__ float As[TK][TM + 4];
    __shared__ float Ws[TK][TN + 4];

    const int tid = threadIdx.x;
    const int th  = tid & 15;
    const int tb  = tid >> 4;
    const int h0  = blockIdx.x * TN;
    const int b0  = blockIdx.y * TM;
    const int z   = blockIdx.z;
    const int kv_base = z * kchunk;

    float acc[4][8];
    #pragma unroll
    for (int i = 0; i < 4; ++i)
        #pragma unroll
        for (int j = 0; j < 8; ++j) acc[i][j] = 0.0f;

    float4 xv[2], wv[4];

    auto load_regs = [&](int t) {
        int kv = kv_base + t * TK;
        const float* X; const float* W; int k0;
        if (kv < 1024) { X = ha; W = Wha; k0 = kv; }
        else           { X = hf; W = Whf; k0 = kv - 1024; }
        #pragma unroll
        for (int r = 0; r < 2; ++r) {
            int idx = tid + r * 256;
            int row = idx >> 3, kq = idx & 7;
            xv[r] = *reinterpret_cast<const float4*>(X + (size_t)(b0 + row) * Hdim + k0 + kq * 4);
        }
        #pragma unroll
        for (int r = 0; r < 4; ++r) {
            int idx = tid + r * 256;
            int row = idx >> 3, kq = idx & 7;
            wv[r] = *reinterpret_cast<const float4*>(W + (size_t)(h0 + row) * Hdim + k0 + kq * 4);
        }
    };

    const int ntiles = kchunk / TK;
    load_regs(0);

    for (int t = 0; t < ntiles; ++t) {
        #pragma unroll
        for (int r = 0; r < 2; ++r) {
            int idx = tid + r * 256;
            int row = idx >> 3, kq = idx & 7;
            As[kq * 4 + 0][row] = xv[r].x;
            As[kq * 4 + 1][row] = xv[r].y;
            As[kq * 4 + 2][row] = xv[r].z;
            As[kq * 4 + 3][row] = xv[r].w;
        }
        #pragma unroll
        for (int r = 0; r < 4; ++r) {
            int idx = tid + r * 256;
            int row = idx >> 3, kq = idx & 7;
            Ws[kq * 4 + 0][row] = wv[r].x;
            Ws[kq * 4 + 1][row] = wv[r].y;
            Ws[kq * 4 + 2][row] = wv[r].z;
            Ws[kq * 4 + 3][row] = wv[r].w;
        }
        __syncthreads();

        if (t + 1 < ntiles) load_regs(t + 1);

        #pragma unroll
        for (int k = 0; k < TK; ++k) {
            float4 a0 = *reinterpret_cast<const float4*>(&As[k][tb * 4]);
            float4 w0 = *reinterpret_cast<const float4*>(&Ws[k][th * 8]);
            float4 w1 = *reinterpret_cast<const float4*>(&Ws[k][th * 8 + 4]);
            float a[4] = {a0.x, a0.y, a0.z, a0.w};
            float w[8] = {w0.x, w0.y, w0.z, w0.w, w1.x, w1.y, w1.z, w1.w};
            #pragma unroll
            for (int i = 0; i < 4; ++i)
                #pragma unroll
                for (int j = 0; j < 8; ++j)
                    acc[i][j] += a[i] * w[j];
        }
        __syncthreads();
    }

    #pragma unroll
    for (int i = 0; i < 4; ++i) {
        int b = b0 + tb * 4 + i;
        float* dst = qpart + (size_t)z * BH + (size_t)b * Hdim + h0 + th * 8;
        float4 o0 = {acc[i][0], acc[i][1], acc[i][2], acc[i][3]};
        float4 o1 = {acc[i][4], acc[i][5], acc[i][6], acc[i][7]};
        *reinterpret_cast<float4*>(dst)     = o0;
        *reinterpret_cast<float4*>(dst + 4) = o1;
    }
}

// ------------- Fused online: reduce-q + scores + softmax + att_res in one pass --
// one block per b; 1024 threads = 8 groups of 128. Per 8-row chunk: groups
// compute scores (tanh reduce), online-softmax update, weighted att accumulate.
// score_s = sum_wa - 2*sum_h wa[h]*rcp(exp2(C*(p+q))+1) + b_alpha
__global__ __launch_bounds__(1024) void fused_online(
    const float* __restrict__ qpart, const float* __restrict__ b_ha,
    const float* __restrict__ b_hf,  const float* __restrict__ p_att,
    const float* __restrict__ w_alpha, const float* __restrict__ b_alpha,
    const float* __restrict__ att_feats, float* __restrict__ out, int ks)
{
    __shared__ float qs2[Hdim];      // q * 2log2e
    __shared__ float wa_s[Hdim];     // w_alpha
    __shared__ float part[16];       // per (group,wave) score partials
    __shared__ float wred[4];        // sum(w_alpha) reduction
    __shared__ float buf[Fdim];      // final U combine

    const int b   = blockIdx.x;
    const int tid = threadIdx.x;

    // ---- prologue: reduce qpart + biases -> qs2 (pre-scaled); stage wa; sum(wa) --
    if (tid < 256) {
        size_t off = (size_t)b * Hdim + tid * 4;
        float4 s = {0.f, 0.f, 0.f, 0.f};
        for (int z = 0; z < ks; ++z) {
            float4 v = *reinterpret_cast<const float4*>(qpart + (size_t)z * BH + off);
            s.x += v.x; s.y += v.y; s.z += v.z; s.w += v.w;
        }
        float4 ba = *reinterpret_cast<const float4*>(b_ha + tid * 4);
        float4 bb = *reinterpret_cast<const float4*>(b_hf + tid * 4);
        s.x = (s.x + ba.x + bb.x) * C2L;
        s.y = (s.y + ba.y + bb.y) * C2L;
        s.z = (s.z + ba.z + bb.z) * C2L;
        s.w = (s.w + ba.w + bb.w) * C2L;
        *reinterpret_cast<float4*>(qs2 + tid * 4) = s;
        float4 w = *reinterpret_cast<const float4*>(w_alpha + tid * 4);
        *reinterpret_cast<float4*>(wa_s + tid * 4) = w;
        float ls = w.x + w.y + w.z + w.w;
        #pragma unroll
        for (int m = 32; m >= 1; m >>= 1) ls += __shfl_xor(ls, m, 64);
        if ((tid & 63) == 0) wred[tid >> 6] = ls;
    }
    __syncthreads();

    const float base_sc = wred[0] + wred[1] + wred[2] + wred[3] + b_alpha[0];

    const int g    = tid >> 7;        // group 0..7 (one s-row per group per chunk)
    const int gt   = tid & 127;       // thread within group
    const int lane = tid & 63;
    const int wv   = (tid >> 6) & 1;  // wave within group

    float m_run = -1e30f, d_run = 0.0f;
    float4 U[4];
    #pragma unroll
    for (int j = 0; j < 4; ++j) U[j] = make_float4(0.f, 0.f, 0.f, 0.f);

    const float* pbase = p_att     + (size_t)b * Sdim * Hdim;
    const float* abase = att_feats + (size_t)b * Sdim * Fdim;

    const float4 q0 = *reinterpret_cast<const float4*>(qs2 + gt * 4);
    const float4 q1 = *reinterpret_cast<const float4*>(qs2 + 512 + gt * 4);
    const float4 w0 = *reinterpret_cast<const float4*>(wa_s + gt * 4);
    const float4 w1 = *reinterpret_cast<const float4*>(wa_s + 512 + gt * 4);

    #define NCH 25
    for (int c = 0; c < NCH; ++c) {
        const int s = c * 8 + g;

        // -- score partial: 8 h-elems per thread (two coalesced float4 streams) --
        float psum = 0.0f;
        if (s < Sdim) {
            const float* prow = pbase + (size_t)s * Hdim;
            float4 p0 = *reinterpret_cast<const float4*>(prow + gt * 4);
            float4 p1 = *reinterpret_cast<const float4*>(prow + 512 + gt * 4);
            psum += w0.x * __builtin_amdgcn_rcpf(__builtin_amdgcn_exp2f(fmaf(p0.x, C2L, q0.x)) + 1.0f);
            psum += w0.y * __builtin_amdgcn_rcpf(__builtin_amdgcn_exp2f(fmaf(p0.y, C2L, q0.y)) + 1.0f);
            psum += w0.z * __builtin_amdgcn_rcpf(__builtin_amdgcn_exp2f(fmaf(p0.z, C2L, q0.z)) + 1.0f);
            psum += w0.w * __builtin_amdgcn_rcpf(__builtin_amdgcn_exp2f(fmaf(p0.w, C2L, q0.w)) + 1.0f);
            psum += w1.x * __builtin_amdgcn_rcpf(__builtin_amdgcn_exp2f(fmaf(p1.x, C2L, q1.x)) + 1.0f);
            psum += w1.y * __builtin_amdgcn_rcpf(__builtin_amdgcn_exp2f(fmaf(p1.y, C2L, q1.y)) + 1.0f);
            psum += w1.z * __builtin_amdgcn_rcpf(__builtin_amdgcn_exp2f(fmaf(p1.z, C2L, q1.z)) + 1.0f);
            psum += w1.w * __builtin_amdgcn_rcpf(__builtin_amdgcn_exp2f(fmaf(p1.w, C2L, q1.w)) + 1.0f);
        }
        #pragma unroll
        for (int m = 32; m >= 1; m >>= 1) psum += __shfl_xor(psum, m, 64);
        if (lane == 0) part[g * 2 + wv] = psum;
        __syncthreads();                                   // S1: partials visible

        // -- all threads: form 8 scores, online-softmax update --
        float scv[8];
        #pragma unroll
        for (int gg = 0; gg < 8; ++gg) {
            scv[gg] = (c * 8 + gg < Sdim)
                    ? base_sc - 2.0f * (part[2 * gg] + part[2 * gg + 1])
                    : -1e30f;
        }
        float m_new = m_run;
        #pragma unroll
        for (int gg = 0; gg < 8; ++gg) m_new = fmaxf(m_new, scv[gg]);
        if (m_new > m_run) {
            float scale = __builtin_amdgcn_exp2f((m_run - m_new) * L2E);
            #pragma unroll
            for (int j = 0; j < 4; ++j) {
                U[j].x *= scale; U[j].y *= scale; U[j].z *= scale; U[j].w *= scale;
            }
            d_run *= scale;
            m_run = m_new;
        }
        #pragma unroll
        for (int gg = 0; gg < 8; ++gg)
            d_run += __builtin_amdgcn_exp2f((scv[gg] - m_run) * L2E);

        // own row weight (runtime-indexed LDS reads, no register indexing)
        float own_sc = base_sc - 2.0f * (part[2 * g] + part[2 * g + 1]);
        float w_own  = (s < Sdim) ? __builtin_amdgcn_exp2f((own_sc - m_run) * L2E) : 0.0f;
        __syncthreads();                                   // S2: part[] reusable

        // -- weighted accumulate of this group's att row (overlaps next tanh) --
        if (s < Sdim) {
            const float* arow = abase + (size_t)s * Fdim + gt * 4;
            #pragma unroll
            for (int j = 0; j < 4; ++j) {
                float4 v = *reinterpret_cast<const float4*>(arow + 512 * j);
                U[j].x += w_own * v.x; U[j].y += w_own * v.y;
                U[j].z += w_own * v.z; U[j].w += w_own * v.w;
            }
        }
    }

    // ---- combine U across the 8 groups (partial over s-subsets) ----
    for (int gg = 0; gg < 8; ++gg) {
        if (g == gg) {
            #pragma unroll
            for (int j = 0; j < 4; ++j) {
                float* dst = buf + gt * 4 + 512 * j;
                if (gg == 0) {
                    *reinterpret_cast<float4*>(dst) = U[j];
                } else {
                    float4 v = *reinterpret_cast<const float4*>(dst);
                    v.x += U[j].x; v.y += U[j].y; v.z += U[j].z; v.w += U[j].w;
                    *reinterpret_cast<float4*>(dst) = v;
                }
            }
        }
        __syncthreads();
    }

    if (tid < 512) {
        float rinv = __builtin_amdgcn_rcpf(d_run);
        float4 v = *reinterpret_cast<const float4*>(buf + tid * 4);
        v.x *= rinv; v.y *= rinv; v.z *= rinv; v.w *= rinv;
        *reinterpret_cast<float4*>(out + (size_t)b * Fdim + tid * 4) = v;
    }
}

// ---------------- launch --------------------------------------------------------
extern "C" void kernel_launch(void* const* d_in, const int* in_sizes, int n_in,
                              void* d_out, int out_size, void* d_ws, size_t ws_size,
                              hipStream_t stream) {
    const float* ha       = (const float*)d_in[0];
    const float* hf       = (const float*)d_in[1];
    const float* att_f    = (const float*)d_in[2];
    const float* p_att    = (const float*)d_in[3];
    const float* W_ha     = (const float*)d_in[4];
    const float* b_ha     = (const float*)d_in[5];
    const float* W_hf     = (const float*)d_in[6];
    const float* b_hf     = (const float*)d_in[7];
    const float* w_alpha  = (const float*)d_in[8];
    const float* b_alpha  = (const float*)d_in[9];
    float* out = (float*)d_out;
    float* ws  = (float*)d_ws;

    int KS = 16;
    while (KS > 1 && ((size_t)KS * BH) * sizeof(float) > ws_size) KS >>= 1;

    float* qpart = ws;

    dim3 gA(Hdim / TN, Bdim / TM, KS);
    gemm_q_part<<<gA, 256, 0, stream>>>(ha, hf, W_ha, W_hf, qpart, 2048 / KS);

    fused_online<<<dim3(Bdim), 1024, 0, stream>>>(
        qpart, b_ha, b_hf, p_att, w_alpha, b_alpha, att_f, out, KS);
}

// Round 5
// 122.190 us; speedup vs baseline: 1.1583x; 1.1583x over previous
//
#include <hip/hip_runtime.h>
#include <hip/hip_bf16.h>

#define Bdim 256
#define Sdim 196
#define Hdim 1024
#define Fdim 2048
#define BH (Bdim*Hdim)      // 262144
#define L2E 1.44269504f
#define C2L 2.88539008f     // 2*log2(e)

typedef float nfloat4 __attribute__((ext_vector_type(4)));

__device__ __forceinline__ float4 ldnt4(const float* p) {
    nfloat4 v = __builtin_nontemporal_load(reinterpret_cast<const nfloat4*>(p));
    return make_float4(v.x, v.y, v.z, v.w);
}

// ---------------- Kernel A: q partials = ha@W_ha^T + hf@W_hf^T (K-split) --------
#define TM 64
#define TN 128
#define TK 32

__global__ __launch_bounds__(256) void gemm_q_part(
    const float* __restrict__ ha, const float* __restrict__ hf,
    const float* __restrict__ Wha, const float* __restrict__ Whf,
    float* __restrict__ qpart, int kchunk)
{
    __shared__ float As[TK][TM + 4];
    __shared__ float Ws[TK][TN + 4];

    const int tid = threadIdx.x;
    const int th  = tid & 15;
    const int tb  = tid >> 4;
    const int h0  = blockIdx.x * TN;
    const int b0  = blockIdx.y * TM;
    const int z   = blockIdx.z;
    const int kv_base = z * kchunk;

    float acc[4][8];
    #pragma unroll
    for (int i = 0; i < 4; ++i)
        #pragma unroll
        for (int j = 0; j < 8; ++j) acc[i][j] = 0.0f;

    float4 xv[2], wv[4];

    auto load_regs = [&](int t) {
        int kv = kv_base + t * TK;
        const float* X; const float* W; int k0;
        if (kv < 1024) { X = ha; W = Wha; k0 = kv; }
        else           { X = hf; W = Whf; k0 = kv - 1024; }
        #pragma unroll
        for (int r = 0; r < 2; ++r) {
            int idx = tid + r * 256;
            int row = idx >> 3, kq = idx & 7;
            xv[r] = *reinterpret_cast<const float4*>(X + (size_t)(b0 + row) * Hdim + k0 + kq * 4);
        }
        #pragma unroll
        for (int r = 0; r < 4; ++r) {
            int idx = tid + r * 256;
            int row = idx >> 3, kq = idx & 7;
            wv[r] = *reinterpret_cast<const float4*>(W + (size_t)(h0 + row) * Hdim + k0 + kq * 4);
        }
    };

    const int ntiles = kchunk / TK;
    load_regs(0);

    for (int t = 0; t < ntiles; ++t) {
        #pragma unroll
        for (int r = 0; r < 2; ++r) {
            int idx = tid + r * 256;
            int row = idx >> 3, kq = idx & 7;
            As[kq * 4 + 0][row] = xv[r].x;
            As[kq * 4 + 1][row] = xv[r].y;
            As[kq * 4 + 2][row] = xv[r].z;
            As[kq * 4 + 3][row] = xv[r].w;
        }
        #pragma unroll
        for (int r = 0; r < 4; ++r) {
            int idx = tid + r * 256;
            int row = idx >> 3, kq = idx & 7;
            Ws[kq * 4 + 0][row] = wv[r].x;
            Ws[kq * 4 + 1][row] = wv[r].y;
            Ws[kq * 4 + 2][row] = wv[r].z;
            Ws[kq * 4 + 3][row] = wv[r].w;
        }
        __syncthreads();

        if (t + 1 < ntiles) load_regs(t + 1);

        #pragma unroll
        for (int k = 0; k < TK; ++k) {
            float4 a0 = *reinterpret_cast<const float4*>(&As[k][tb * 4]);
            float4 w0 = *reinterpret_cast<const float4*>(&Ws[k][th * 8]);
            float4 w1 = *reinterpret_cast<const float4*>(&Ws[k][th * 8 + 4]);
            float a[4] = {a0.x, a0.y, a0.z, a0.w};
            float w[8] = {w0.x, w0.y, w0.z, w0.w, w1.x, w1.y, w1.z, w1.w};
            #pragma unroll
            for (int i = 0; i < 4; ++i)
                #pragma unroll
                for (int j = 0; j < 8; ++j)
                    acc[i][j] += a[i] * w[j];
        }
        __syncthreads();
    }

    #pragma unroll
    for (int i = 0; i < 4; ++i) {
        int b = b0 + tb * 4 + i;
        float* dst = qpart + (size_t)z * BH + (size_t)b * Hdim + h0 + th * 8;
        float4 o0 = {acc[i][0], acc[i][1], acc[i][2], acc[i][3]};
        float4 o1 = {acc[i][4], acc[i][5], acc[i][6], acc[i][7]};
        *reinterpret_cast<float4*>(dst)     = o0;
        *reinterpret_cast<float4*>(dst + 4) = o1;
    }
}

// ---------------- Fused: reduce-q + scores + softmax + att_res ------------------
// one block per batch row b; 1024 threads = 16 waves. Phase-serial (R2 struct):
// P0 parallel prologue, P1 scores (q/wa in REGISTERS, row prefetch),
// P2 wave-0 softmax, P3 att accumulate (float4, s-unroll 4, weights via float4).
__global__ __launch_bounds__(1024) void fused_kernel(
    const float* __restrict__ qpart, const float* __restrict__ b_ha,
    const float* __restrict__ b_hf,  const float* __restrict__ p_att,
    const float* __restrict__ w_alpha, const float* __restrict__ b_alpha,
    const float* __restrict__ att_feats, float* __restrict__ out, int ks)
{
    __shared__ __align__(16) float qs2[Hdim];    // C2L*(q + biases)
    __shared__ __align__(16) float wa_s[Hdim];   // w_alpha
    __shared__ __align__(16) float sc[Sdim];     // scores -> unnormalized e
    __shared__ __align__(16) float part[Fdim];   // half-1 partial for combine
    __shared__ __align__(16) float qtmp[3 * Hdim]; // prologue z-split partials
    __shared__ float wred[5];                    // sum(wa) parts + inv_total

    const int b    = blockIdx.x;
    const int tid  = threadIdx.x;
    const int wave = tid >> 6, lane = tid & 63;

    // ---- P0: z-split qpart reduce (groups 0..3) & wa staging (waves 4..7) ----
    {
        const int zg = tid >> 8;        // 0..3
        const int h4 = tid & 255;       // float4 index into H
        size_t off = (size_t)b * Hdim + h4 * 4;
        float4 s = {0.f, 0.f, 0.f, 0.f};
        for (int z = zg; z < ks; z += 4) {
            float4 v = *reinterpret_cast<const float4*>(qpart + (size_t)z * BH + off);
            s.x += v.x; s.y += v.y; s.z += v.z; s.w += v.w;
        }
        if (zg > 0) {
            *reinterpret_cast<float4*>(qtmp + (zg - 1) * Hdim + h4 * 4) = s;
        } else {
            float4 ba = *reinterpret_cast<const float4*>(b_ha + h4 * 4);
            float4 bb = *reinterpret_cast<const float4*>(b_hf + h4 * 4);
            s.x += ba.x + bb.x; s.y += ba.y + bb.y;
            s.z += ba.z + bb.z; s.w += ba.w + bb.w;
            *reinterpret_cast<float4*>(qs2 + h4 * 4) = s;   // temp: pre-combine
        }
        if (zg == 1) {
            float4 w = *reinterpret_cast<const float4*>(w_alpha + h4 * 4);
            *reinterpret_cast<float4*>(wa_s + h4 * 4) = w;
            float ls = w.x + w.y + w.z + w.w;
            #pragma unroll
            for (int m = 32; m >= 1; m >>= 1) ls += __shfl_xor(ls, m, 64);
            if (lane == 0) wred[wave - 4] = ls;
        }
    }
    __syncthreads();

    if (tid < 256) {
        const int h4 = tid;
        float4 s = *reinterpret_cast<const float4*>(qs2 + h4 * 4);
        #pragma unroll
        for (int g = 0; g < 3; ++g) {
            float4 v = *reinterpret_cast<const float4*>(qtmp + g * Hdim + h4 * 4);
            s.x += v.x; s.y += v.y; s.z += v.z; s.w += v.w;
        }
        s.x *= C2L; s.y *= C2L; s.z *= C2L; s.w *= C2L;
        *reinterpret_cast<float4*>(qs2 + h4 * 4) = s;
    }
    __syncthreads();

    const float base_sc = wred[0] + wred[1] + wred[2] + wred[3] + b_alpha[0];

    // ---- P1: scores; q/wa hoisted to registers (lane-invariant across rows) ----
    float4 qr[4], wr[4];
    #pragma unroll
    for (int i = 0; i < 4; ++i) {
        qr[i] = *reinterpret_cast<const float4*>(qs2 + (i * 64 + lane) * 4);
        wr[i] = *reinterpret_cast<const float4*>(wa_s + (i * 64 + lane) * 4);
    }

    const float* pbase = p_att + (size_t)b * Sdim * Hdim;
    {
        int s = wave;
        float4 pv[4];
        #pragma unroll
        for (int i = 0; i < 4; ++i)
            pv[i] = ldnt4(pbase + (size_t)s * Hdim + (i * 64 + lane) * 4);
        while (s < Sdim) {
            const int sn = s + 16;
            float4 pn[4];
            if (sn < Sdim) {
                #pragma unroll
                for (int i = 0; i < 4; ++i)
                    pn[i] = ldnt4(pbase + (size_t)sn * Hdim + (i * 64 + lane) * 4);
            }
            float psum = 0.0f;
            #pragma unroll
            for (int i = 0; i < 4; ++i) {
                psum += wr[i].x * __builtin_amdgcn_rcpf(__builtin_amdgcn_exp2f(fmaf(pv[i].x, C2L, qr[i].x)) + 1.0f);
                psum += wr[i].y * __builtin_amdgcn_rcpf(__builtin_amdgcn_exp2f(fmaf(pv[i].y, C2L, qr[i].y)) + 1.0f);
                psum += wr[i].z * __builtin_amdgcn_rcpf(__builtin_amdgcn_exp2f(fmaf(pv[i].z, C2L, qr[i].z)) + 1.0f);
                psum += wr[i].w * __builtin_amdgcn_rcpf(__builtin_amdgcn_exp2f(fmaf(pv[i].w, C2L, qr[i].w)) + 1.0f);
            }
            #pragma unroll
            for (int m = 32; m >= 1; m >>= 1) psum += __shfl_xor(psum, m, 64);
            if (lane == 0) sc[s] = base_sc - 2.0f * psum;
            #pragma unroll
            for (int i = 0; i < 4; ++i) pv[i] = pn[i];
            s = sn;
        }
    }
    __syncthreads();

    // ---- P2: softmax over sc[0..195] (wave 0); sc <- e, wred[4] <- rcp(sum) ----
    if (wave == 0) {
        float v0 = sc[lane];
        float v1 = sc[lane + 64];
        float v2 = sc[lane + 128];
        float v3 = (lane < Sdim - 192) ? sc[lane + 192] : -1e30f;
        float m = fmaxf(fmaxf(v0, v1), fmaxf(v2, v3));
        #pragma unroll
        for (int mk = 32; mk >= 1; mk >>= 1) m = fmaxf(m, __shfl_xor(m, mk, 64));
        float e0 = __builtin_amdgcn_exp2f((v0 - m) * L2E);
        float e1 = __builtin_amdgcn_exp2f((v1 - m) * L2E);
        float e2 = __builtin_amdgcn_exp2f((v2 - m) * L2E);
        float e3 = (lane < Sdim - 192) ? __builtin_amdgcn_exp2f((v3 - m) * L2E) : 0.0f;
        float ss = e0 + e1 + e2 + e3;
        #pragma unroll
        for (int mk = 32; mk >= 1; mk >>= 1) ss += __shfl_xor(ss, mk, 64);
        sc[lane]       = e0;
        sc[lane + 64]  = e1;
        sc[lane + 128] = e2;
        if (lane < Sdim - 192) sc[lane + 192] = e3;
        if (lane == 0) wred[4] = __builtin_amdgcn_rcpf(ss);
    }
    __syncthreads();

    // ---- P3: att_res accumulate; half 0: s[0,96), half 1: s[96,196) ----
    const int half = tid >> 9;
    const int fi   = (tid & 511) * 4;
    const float* abase = att_feats + (size_t)b * Sdim * Fdim + fi;
    float4 a4 = {0.f, 0.f, 0.f, 0.f};
    const int s0 = half ? 96 : 0;
    const int s1 = half ? 196 : 96;
    for (int s4 = s0; s4 < s1; s4 += 4) {
        float4 w4 = *reinterpret_cast<const float4*>(sc + s4);
        float4 v0 = ldnt4(abase + (size_t)(s4 + 0) * Fdim);
        float4 v1 = ldnt4(abase + (size_t)(s4 + 1) * Fdim);
        float4 v2 = ldnt4(abase + (size_t)(s4 + 2) * Fdim);
        float4 v3 = ldnt4(abase + (size_t)(s4 + 3) * Fdim);
        a4.x += w4.x * v0.x; a4.y += w4.x * v0.y; a4.z += w4.x * v0.z; a4.w += w4.x * v0.w;
        a4.x += w4.y * v1.x; a4.y += w4.y * v1.y; a4.z += w4.y * v1.z; a4.w += w4.y * v1.w;
        a4.x += w4.z * v2.x; a4.y += w4.z * v2.y; a4.z += w4.z * v2.z; a4.w += w4.z * v2.w;
        a4.x += w4.w * v3.x; a4.y += w4.w * v3.y; a4.z += w4.w * v3.z; a4.w += w4.w * v3.w;
    }
    if (half) {
        *reinterpret_cast<float4*>(part + fi) = a4;
    }
    __syncthreads();
    if (!half) {
        const float winv = wred[4];
        float4 p4 = *reinterpret_cast<const float4*>(part + fi);
        a4.x = (a4.x + p4.x) * winv; a4.y = (a4.y + p4.y) * winv;
        a4.z = (a4.z + p4.z) * winv; a4.w = (a4.w + p4.w) * winv;
        *reinterpret_cast<float4*>(out + (size_t)b * Fdim + fi) = a4;
    }
}

// ---------------- launch --------------------------------------------------------
extern "C" void kernel_launch(void* const* d_in, const int* in_sizes, int n_in,
                              void* d_out, int out_size, void* d_ws, size_t ws_size,
                              hipStream_t stream) {
    const float* ha       = (const float*)d_in[0];
    const float* hf       = (const float*)d_in[1];
    const float* att_f    = (const float*)d_in[2];
    const float* p_att    = (const float*)d_in[3];
    const float* W_ha     = (const float*)d_in[4];
    const float* b_ha     = (const float*)d_in[5];
    const float* W_hf     = (const float*)d_in[6];
    const float* b_hf     = (const float*)d_in[7];
    const float* w_alpha  = (const float*)d_in[8];
    const float* b_alpha  = (const float*)d_in[9];
    float* out = (float*)d_out;
    float* ws  = (float*)d_ws;

    int KS = 16;
    while (KS > 1 && ((size_t)KS * BH) * sizeof(float) > ws_size) KS >>= 1;

    float* qpart = ws;

    dim3 gA(Hdim / TN, Bdim / TM, KS);
    gemm_q_part<<<gA, 256, 0, stream>>>(ha, hf, W_ha, W_hf, qpart, 2048 / KS);

    fused_kernel<<<dim3(Bdim), 1024, 0, stream>>>(
        qpart, b_ha, b_hf, p_att, w_alpha, b_alpha, att_f, out, KS);
}

// Round 6
// 120.533 us; speedup vs baseline: 1.1743x; 1.0137x over previous
//
#include <hip/hip_runtime.h>
#include <hip/hip_bf16.h>
#include <hip/hip_fp16.h>

#define Bdim 256
#define Sdim 196
#define Hdim 1024
#define Fdim 2048
#define BH (Bdim*Hdim)      // 262144
#define L2E 1.44269504f
#define C2L 2.88539008f     // 2*log2(e)

typedef float nfloat4 __attribute__((ext_vector_type(4)));

__device__ __forceinline__ float4 ldnt4(const float* p) {
    nfloat4 v = __builtin_nontemporal_load(reinterpret_cast<const nfloat4*>(p));
    return make_float4(v.x, v.y, v.z, v.w);
}

// ---------------- Kernel A: qpart(fp16) = slices of ha@W_ha^T + hf@W_hf^T -------
// TM=128 x TN=128, TK=32; 256 threads, micro 8x8; K-split KS=16 (kchunk=128)
#define TM 128
#define TN 128
#define TK 32

__global__ __launch_bounds__(256) void gemm_q_part(
    const float* __restrict__ ha, const float* __restrict__ hf,
    const float* __restrict__ Wha, const float* __restrict__ Whf,
    __half* __restrict__ qpart, int kchunk)
{
    __shared__ float As[TK][TM + 4];
    __shared__ float Ws[TK][TN + 4];

    const int tid = threadIdx.x;
    const int th  = tid & 15;          // h-group: 16 * 8 = 128
    const int tb  = tid >> 4;          // b-group: 16 * 8 = 128
    const int h0  = blockIdx.x * TN;
    const int b0  = blockIdx.y * TM;
    const int z   = blockIdx.z;
    const int kv_base = z * kchunk;

    float acc[8][8];
    #pragma unroll
    for (int i = 0; i < 8; ++i)
        #pragma unroll
        for (int j = 0; j < 8; ++j) acc[i][j] = 0.0f;

    float4 xv[4], wv[4];

    auto load_regs = [&](int t) {
        int kv = kv_base + t * TK;
        const float* X; const float* W; int k0;
        if (kv < 1024) { X = ha; W = Wha; k0 = kv; }
        else           { X = hf; W = Whf; k0 = kv - 1024; }
        #pragma unroll
        for (int r = 0; r < 4; ++r) {
            int idx = tid + r * 256;
            int row = idx >> 3, kq = idx & 7;
            xv[r] = *reinterpret_cast<const float4*>(X + (size_t)(b0 + row) * Hdim + k0 + kq * 4);
            wv[r] = *reinterpret_cast<const float4*>(W + (size_t)(h0 + row) * Hdim + k0 + kq * 4);
        }
    };

    const int ntiles = kchunk / TK;
    load_regs(0);

    for (int t = 0; t < ntiles; ++t) {
        #pragma unroll
        for (int r = 0; r < 4; ++r) {
            int idx = tid + r * 256;
            int row = idx >> 3, kq = idx & 7;
            As[kq * 4 + 0][row] = xv[r].x;
            As[kq * 4 + 1][row] = xv[r].y;
            As[kq * 4 + 2][row] = xv[r].z;
            As[kq * 4 + 3][row] = xv[r].w;
            Ws[kq * 4 + 0][row] = wv[r].x;
            Ws[kq * 4 + 1][row] = wv[r].y;
            Ws[kq * 4 + 2][row] = wv[r].z;
            Ws[kq * 4 + 3][row] = wv[r].w;
        }
        __syncthreads();

        if (t + 1 < ntiles) load_regs(t + 1);

        #pragma unroll
        for (int k = 0; k < TK; ++k) {
            float4 a0 = *reinterpret_cast<const float4*>(&As[k][tb * 8]);
            float4 a1 = *reinterpret_cast<const float4*>(&As[k][tb * 8 + 4]);
            float4 w0 = *reinterpret_cast<const float4*>(&Ws[k][th * 8]);
            float4 w1 = *reinterpret_cast<const float4*>(&Ws[k][th * 8 + 4]);
            float a[8] = {a0.x, a0.y, a0.z, a0.w, a1.x, a1.y, a1.z, a1.w};
            float w[8] = {w0.x, w0.y, w0.z, w0.w, w1.x, w1.y, w1.z, w1.w};
            #pragma unroll
            for (int i = 0; i < 8; ++i)
                #pragma unroll
                for (int j = 0; j < 8; ++j)
                    acc[i][j] += a[i] * w[j];
        }
        __syncthreads();
    }

    #pragma unroll
    for (int i = 0; i < 8; ++i) {
        int b = b0 + tb * 8 + i;
        __half* dst = qpart + (size_t)z * BH + (size_t)b * Hdim + h0 + th * 8;
        __half2* dst2 = reinterpret_cast<__half2*>(dst);
        dst2[0] = __floats2half2_rn(acc[i][0], acc[i][1]);
        dst2[1] = __floats2half2_rn(acc[i][2], acc[i][3]);
        dst2[2] = __floats2half2_rn(acc[i][4], acc[i][5]);
        dst2[3] = __floats2half2_rn(acc[i][6], acc[i][7]);
    }
}

// ---------------- Fused: reduce-q + scores + softmax + att_res ------------------
// one block per b; 1024 threads = 16 waves. P0 parallel prologue (fp16 qpart),
// P1 scores (q/wa in regs, row prefetch, nontemporal), P2 redundant per-wave
// softmax (no extra barrier), P3 att accumulate (s-unroll 8, on-the-fly exp2).
__global__ __launch_bounds__(1024) void fused_kernel(
    const __half* __restrict__ qpart, const float* __restrict__ b_ha,
    const float* __restrict__ b_hf,  const float* __restrict__ p_att,
    const float* __restrict__ w_alpha, const float* __restrict__ b_alpha,
    const float* __restrict__ att_feats, float* __restrict__ out, int ks)
{
    __shared__ __align__(16) float qs2[Hdim];      // C2L*(q + biases)
    __shared__ __align__(16) float wa_s[Hdim];     // w_alpha
    __shared__ __align__(16) float sc[Sdim];       // raw scores
    __shared__ __align__(16) float part[Fdim];     // half-1 partial for combine
    __shared__ __align__(16) float qtmp[3 * Hdim]; // prologue z-split partials
    __shared__ float wred[4];                      // sum(wa) parts

    const int b    = blockIdx.x;
    const int tid  = threadIdx.x;
    const int wave = tid >> 6, lane = tid & 63;

    // ---- P0: z-split qpart reduce (4 groups) & wa staging ----
    {
        const int zg = tid >> 8;        // 0..3
        const int h4 = tid & 255;       // float4 index into H
        size_t off = (size_t)b * Hdim + h4 * 4;
        float4 s = {0.f, 0.f, 0.f, 0.f};
        for (int z = zg; z < ks; z += 4) {
            const __half2* p2 = reinterpret_cast<const __half2*>(qpart + (size_t)z * BH + off);
            float2 f0 = __half22float2(p2[0]);
            float2 f1 = __half22float2(p2[1]);
            s.x += f0.x; s.y += f0.y; s.z += f1.x; s.w += f1.y;
        }
        if (zg > 0) {
            *reinterpret_cast<float4*>(qtmp + (zg - 1) * Hdim + h4 * 4) = s;
        } else {
            float4 ba = *reinterpret_cast<const float4*>(b_ha + h4 * 4);
            float4 bb = *reinterpret_cast<const float4*>(b_hf + h4 * 4);
            s.x += ba.x + bb.x; s.y += ba.y + bb.y;
            s.z += ba.z + bb.z; s.w += ba.w + bb.w;
            *reinterpret_cast<float4*>(qs2 + h4 * 4) = s;   // pre-combine
        }
        if (zg == 1) {
            float4 w = *reinterpret_cast<const float4*>(w_alpha + h4 * 4);
            *reinterpret_cast<float4*>(wa_s + h4 * 4) = w;
            float ls = w.x + w.y + w.z + w.w;
            #pragma unroll
            for (int m = 32; m >= 1; m >>= 1) ls += __shfl_xor(ls, m, 64);
            if (lane == 0) wred[wave - 4] = ls;
        }
    }
    __syncthreads();

    if (tid < 256) {
        const int h4 = tid;
        float4 s = *reinterpret_cast<const float4*>(qs2 + h4 * 4);
        #pragma unroll
        for (int g = 0; g < 3; ++g) {
            float4 v = *reinterpret_cast<const float4*>(qtmp + g * Hdim + h4 * 4);
            s.x += v.x; s.y += v.y; s.z += v.z; s.w += v.w;
        }
        s.x *= C2L; s.y *= C2L; s.z *= C2L; s.w *= C2L;
        *reinterpret_cast<float4*>(qs2 + h4 * 4) = s;
    }
    __syncthreads();

    const float base_sc = wred[0] + wred[1] + wred[2] + wred[3] + b_alpha[0];

    // ---- P1: scores; q/wa in registers (lane-invariant across rows) ----
    float4 qr[4], wr[4];
    #pragma unroll
    for (int i = 0; i < 4; ++i) {
        qr[i] = *reinterpret_cast<const float4*>(qs2 + (i * 64 + lane) * 4);
        wr[i] = *reinterpret_cast<const float4*>(wa_s + (i * 64 + lane) * 4);
    }

    const float* pbase = p_att + (size_t)b * Sdim * Hdim;
    {
        int s = wave;
        float4 pv[4];
        #pragma unroll
        for (int i = 0; i < 4; ++i)
            pv[i] = ldnt4(pbase + (size_t)s * Hdim + (i * 64 + lane) * 4);
        while (s < Sdim) {
            const int sn = s + 16;
            float4 pn[4];
            if (sn < Sdim) {
                #pragma unroll
                for (int i = 0; i < 4; ++i)
                    pn[i] = ldnt4(pbase + (size_t)sn * Hdim + (i * 64 + lane) * 4);
            }
            float psum = 0.0f;
            #pragma unroll
            for (int i = 0; i < 4; ++i) {
                psum += wr[i].x * __builtin_amdgcn_rcpf(__builtin_amdgcn_exp2f(fmaf(pv[i].x, C2L, qr[i].x)) + 1.0f);
                psum += wr[i].y * __builtin_amdgcn_rcpf(__builtin_amdgcn_exp2f(fmaf(pv[i].y, C2L, qr[i].y)) + 1.0f);
                psum += wr[i].z * __builtin_amdgcn_rcpf(__builtin_amdgcn_exp2f(fmaf(pv[i].z, C2L, qr[i].z)) + 1.0f);
                psum += wr[i].w * __builtin_amdgcn_rcpf(__builtin_amdgcn_exp2f(fmaf(pv[i].w, C2L, qr[i].w)) + 1.0f);
            }
            #pragma unroll
            for (int m = 32; m >= 1; m >>= 1) psum += __shfl_xor(psum, m, 64);
            if (lane == 0) sc[s] = base_sc - 2.0f * psum;
            #pragma unroll
            for (int i = 0; i < 4; ++i) pv[i] = pn[i];
            s = sn;
        }
    }
    __syncthreads();

    // ---- P2: redundant per-wave softmax stats (no LDS writes, no barrier) ----
    float m_max, ssum;
    {
        float v0 = sc[lane];
        float v1 = sc[lane + 64];
        float v2 = sc[lane + 128];
        float v3 = (lane < Sdim - 192) ? sc[lane + 192] : -1e30f;
        float m = fmaxf(fmaxf(v0, v1), fmaxf(v2, v3));
        #pragma unroll
        for (int mk = 32; mk >= 1; mk >>= 1) m = fmaxf(m, __shfl_xor(m, mk, 64));
        float e0 = __builtin_amdgcn_exp2f((v0 - m) * L2E);
        float e1 = __builtin_amdgcn_exp2f((v1 - m) * L2E);
        float e2 = __builtin_amdgcn_exp2f((v2 - m) * L2E);
        float e3 = (lane < Sdim - 192) ? __builtin_amdgcn_exp2f((v3 - m) * L2E) : 0.0f;
        float ss = e0 + e1 + e2 + e3;
        #pragma unroll
        for (int mk = 32; mk >= 1; mk >>= 1) ss += __shfl_xor(ss, mk, 64);
        m_max = m; ssum = ss;
    }

    // ---- P3: att_res accumulate; e = exp2((sc-m)*L2E) on the fly ----
    const int half = tid >> 9;
    const int fi   = (tid & 511) * 4;
    const float* abase = att_feats + (size_t)b * Sdim * Fdim + fi;
    float4 a4 = {0.f, 0.f, 0.f, 0.f};
    const int s0 = half ? 96 : 0;
    const int s1 = half ? 196 : 96;
    int s4 = s0;
    for (; s4 + 8 <= s1; s4 += 8) {
        float4 sa = *reinterpret_cast<const float4*>(sc + s4);
        float4 sb = *reinterpret_cast<const float4*>(sc + s4 + 4);
        float4 v0 = ldnt4(abase + (size_t)(s4 + 0) * Fdim);
        float4 v1 = ldnt4(abase + (size_t)(s4 + 1) * Fdim);
        float4 v2 = ldnt4(abase + (size_t)(s4 + 2) * Fdim);
        float4 v3 = ldnt4(abase + (size_t)(s4 + 3) * Fdim);
        float4 v4 = ldnt4(abase + (size_t)(s4 + 4) * Fdim);
        float4 v5 = ldnt4(abase + (size_t)(s4 + 5) * Fdim);
        float4 v6 = ldnt4(abase + (size_t)(s4 + 6) * Fdim);
        float4 v7 = ldnt4(abase + (size_t)(s4 + 7) * Fdim);
        float e0 = __builtin_amdgcn_exp2f((sa.x - m_max) * L2E);
        float e1 = __builtin_amdgcn_exp2f((sa.y - m_max) * L2E);
        float e2 = __builtin_amdgcn_exp2f((sa.z - m_max) * L2E);
        float e3 = __builtin_amdgcn_exp2f((sa.w - m_max) * L2E);
        float e4 = __builtin_amdgcn_exp2f((sb.x - m_max) * L2E);
        float e5 = __builtin_amdgcn_exp2f((sb.y - m_max) * L2E);
        float e6 = __builtin_amdgcn_exp2f((sb.z - m_max) * L2E);
        float e7 = __builtin_amdgcn_exp2f((sb.w - m_max) * L2E);
        a4.x += e0 * v0.x; a4.y += e0 * v0.y; a4.z += e0 * v0.z; a4.w += e0 * v0.w;
        a4.x += e1 * v1.x; a4.y += e1 * v1.y; a4.z += e1 * v1.z; a4.w += e1 * v1.w;
        a4.x += e2 * v2.x; a4.y += e2 * v2.y; a4.z += e2 * v2.z; a4.w += e2 * v2.w;
        a4.x += e3 * v3.x; a4.y += e3 * v3.y; a4.z += e3 * v3.z; a4.w += e3 * v3.w;
        a4.x += e4 * v4.x; a4.y += e4 * v4.y; a4.z += e4 * v4.z; a4.w += e4 * v4.w;
        a4.x += e5 * v5.x; a4.y += e5 * v5.y; a4.z += e5 * v5.z; a4.w += e5 * v5.w;
        a4.x += e6 * v6.x; a4.y += e6 * v6.y; a4.z += e6 * v6.z; a4.w += e6 * v6.w;
        a4.x += e7 * v7.x; a4.y += e7 * v7.y; a4.z += e7 * v7.z; a4.w += e7 * v7.w;
    }
    if (s4 < s1) {   // tail of 4 (only half 1: s = 192..195)
        float4 sa = *reinterpret_cast<const float4*>(sc + s4);
        float4 v0 = ldnt4(abase + (size_t)(s4 + 0) * Fdim);
        float4 v1 = ldnt4(abase + (size_t)(s4 + 1) * Fdim);
        float4 v2 = ldnt4(abase + (size_t)(s4 + 2) * Fdim);
        float4 v3 = ldnt4(abase + (size_t)(s4 + 3) * Fdim);
        float e0 = __builtin_amdgcn_exp2f((sa.x - m_max) * L2E);
        float e1 = __builtin_amdgcn_exp2f((sa.y - m_max) * L2E);
        float e2 = __builtin_amdgcn_exp2f((sa.z - m_max) * L2E);
        float e3 = __builtin_amdgcn_exp2f((sa.w - m_max) * L2E);
        a4.x += e0 * v0.x; a4.y += e0 * v0.y; a4.z += e0 * v0.z; a4.w += e0 * v0.w;
        a4.x += e1 * v1.x; a4.y += e1 * v1.y; a4.z += e1 * v1.z; a4.w += e1 * v1.w;
        a4.x += e2 * v2.x; a4.y += e2 * v2.y; a4.z += e2 * v2.z; a4.w += e2 * v2.w;
        a4.x += e3 * v3.x; a4.y += e3 * v3.y; a4.z += e3 * v3.z; a4.w += e3 * v3.w;
    }
    if (half) {
        *reinterpret_cast<float4*>(part + fi) = a4;
    }
    __syncthreads();
    if (!half) {
        const float winv = __builtin_amdgcn_rcpf(ssum);
        float4 p4 = *reinterpret_cast<const float4*>(part + fi);
        a4.x = (a4.x + p4.x) * winv; a4.y = (a4.y + p4.y) * winv;
        a4.z = (a4.z + p4.z) * winv; a4.w = (a4.w + p4.w) * winv;
        *reinterpret_cast<float4*>(out + (size_t)b * Fdim + fi) = a4;
    }
}

// ---------------- launch --------------------------------------------------------
extern "C" void kernel_launch(void* const* d_in, const int* in_sizes, int n_in,
                              void* d_out, int out_size, void* d_ws, size_t ws_size,
                              hipStream_t stream) {
    const float* ha       = (const float*)d_in[0];
    const float* hf       = (const float*)d_in[1];
    const float* att_f    = (const float*)d_in[2];
    const float* p_att    = (const float*)d_in[3];
    const float* W_ha     = (const float*)d_in[4];
    const float* b_ha     = (const float*)d_in[5];
    const float* W_hf     = (const float*)d_in[6];
    const float* b_hf     = (const float*)d_in[7];
    const float* w_alpha  = (const float*)d_in[8];
    const float* b_alpha  = (const float*)d_in[9];
    float* out = (float*)d_out;
    __half* qpart = (__half*)d_ws;

    int KS = 16;
    while (KS > 1 && ((size_t)KS * BH) * sizeof(__half) > ws_size) KS >>= 1;

    dim3 gA(Hdim / TN, Bdim / TM, KS);
    gemm_q_part<<<gA, 256, 0, stream>>>(ha, hf, W_ha, W_hf, qpart, 2048 / KS);

    fused_kernel<<<dim3(Bdim), 1024, 0, stream>>>(
        qpart, b_ha, b_hf, p_att, w_alpha, b_alpha, att_f, out, KS);
}